// Round 3
// baseline (2398.097 us; speedup 1.0000x reference)
//
#include <hip/hip_runtime.h>
#include <math.h>

typedef unsigned short u16;
typedef unsigned int u32;
typedef __attribute__((ext_vector_type(4))) float f32x4;

#define DIM 384
#define HID 1536

static __device__ __forceinline__ float bf2f(u32 b){ return __uint_as_float(b << 16); }
static __device__ __forceinline__ u16 f2bf(float f){
  u32 u = __float_as_uint(f);
  u32 r = (u + 0x7fffu + ((u >> 16) & 1u)) >> 16;
  return (u16)r;
}
static __device__ __forceinline__ float ldf(u16 v){ return bf2f((u32)v); }
static __device__ __forceinline__ float ldf(float v){ return v; }
static __device__ __forceinline__ void stf(u16* p, float v){ *p = f2bf(v); }
static __device__ __forceinline__ void stf(float* p, float v){ *p = v; }
static __device__ __forceinline__ float gelu_exact(float v){
  return 0.5f * v * (1.0f + erff(v * 0.70710678118654752f));
}
// dtype probe: norm1_scale is all-ones. bf16 -> 0x3F803F80, f32 -> 0x3F800000
static __device__ __forceinline__ int probe_is_bf16(const u32* p){ return p[0] == 0x3F803F80u; }

// ---------------- LayerNorm: TX source, TP scale/bias, bf16 out -------------
template<typename TX, typename TP>
__global__ __launch_bounds__(256) void ln_k(const u32* __restrict__ probe, int want,
    const TX* __restrict__ x, const TP* __restrict__ sc, const TP* __restrict__ bi,
    u16* __restrict__ y){
  if (want != 2 && probe_is_bf16(probe) != want) return;
  int lane = threadIdx.x & 63;
  int row = blockIdx.x * 4 + (threadIdx.x >> 6);
  const TX* xr = x + (size_t)row * DIM;
  float v[6];
  float s = 0.f, sq = 0.f;
#pragma unroll
  for (int i = 0; i < 6; ++i){
    float f = ldf(xr[lane + 64*i]);
    v[i] = f; s += f; sq += f*f;
  }
#pragma unroll
  for (int o = 1; o < 64; o <<= 1){ s += __shfl_xor(s, o); sq += __shfl_xor(sq, o); }
  float mean = s * (1.0f/DIM);
  float var = sq * (1.0f/DIM) - mean*mean;
  float inv = rsqrtf(var + 1e-5f);
  u16* yr = y + (size_t)row * DIM;
#pragma unroll
  for (int i = 0; i < 6; ++i){
    int c = lane + 64*i;
    float o = (v[i] - mean) * inv * ldf(sc[c]) + ldf(bi[c]);
    yr[c] = f2bf(o);
  }
}

// ---------------- 3D RoPE, in-place on q (bf16, mode-independent) ----------
__global__ __launch_bounds__(256) void rope_kernel(u16* __restrict__ q,
    const int* __restrict__ Tp, const int* __restrict__ Hp, const int* __restrict__ Wp,
    int Mtok){
  int idx = blockIdx.x * 256 + threadIdx.x;   // one thread per rotated pair
  int tok = idx / 192;                         // 192 pairs per token
  if (tok >= Mtok) return;
  int p = idx - tok * 192;
  int H = *Hp, W = *Wp, T = *Tp;
  int HW = H * W;
  int Ns = T * HW;
  int n = tok % Ns;
  int head = p / 12;
  int pp = p - head * 12;
  int s = pp >> 2, f = pp & 3;
  float pos;
  if (s == 0)      pos = (float)(n / HW);
  else if (s == 1) pos = (float)((n / W) % H);
  else             pos = (float)(n % W);
  const float LOG2_10000 = 13.28771237954945f;
  float inv = exp2f(-0.25f * (float)f * LOG2_10000);
  float ang = pos * inv;
  float sn = sinf(ang), cs = cosf(ang);
  size_t base = (size_t)tok * DIM + head * 24 + s * 8 + 2 * f;
  u32 u = *(u32*)(q + base);
  float x1 = bf2f(u & 0xffffu), x2 = bf2f(u >> 16);
  float y1 = x1 * cs - x2 * sn;
  float y2 = x1 * sn + x2 * cs;
  *(u32*)(q + base) = (u32)f2bf(y1) | ((u32)f2bf(y2) << 16);
}

// ---------------- Naive-but-tiled vector GEMM ------------------------------
// C[M,N] = A[M,K] @ B[K,N] (+bias etc). A is bf16 [M][K]; B/bias/res are TW
// (input dtype); C is TOUT. 64x64 block tile, 4x4 per thread, f32 accumulate.
enum { E_NONE = 0, E_BIAS = 1, E_BIAS_GELU = 2, E_RES_F32 = 3, E_ACC_F32 = 4, E_FINAL = 5 };

template<typename TW, typename TOUT, int EPI>
__global__ __launch_bounds__(256) void ngemm(const u32* __restrict__ probe, int want,
    const u16* __restrict__ A, const TW* __restrict__ B,
    TOUT* __restrict__ C, const TW* __restrict__ bias,
    const TW* __restrict__ res, float* __restrict__ accbuf,
    int K, int N){
  if (want != 2 && probe_is_bf16(probe) != want) return;
  __shared__ __align__(16) float Asd[32][68];   // [k][m], padded
  __shared__ __align__(16) float Bsd[32][68];   // [k][n], padded
  const int tid = threadIdx.x;
  const int tx = tid & 15, ty = tid >> 4;
  const size_t m0 = (size_t)blockIdx.y * 64;
  const int n0 = blockIdx.x * 64;
  float acc[4][4] = {};

  for (int kt = 0; kt < K; kt += 32){
#pragma unroll
    for (int it = 0; it < 8; ++it){
      int idx = it * 256 + tid;
      int kk = idx & 31, row = idx >> 5;      // 32 k x 64 m
      Asd[kk][row] = bf2f((u32)A[(m0 + row) * K + kt + kk]);
    }
#pragma unroll
    for (int it = 0; it < 8; ++it){
      int idx = it * 256 + tid;
      int nn = idx & 63, kk = idx >> 6;       // 32 k x 64 n, coalesced in n
      Bsd[kk][nn] = ldf(B[(size_t)(kt + kk) * N + n0 + nn]);
    }
    __syncthreads();
#pragma unroll
    for (int kk = 0; kk < 32; ++kk){
      f32x4 a = *(const f32x4*)&Asd[kk][ty * 4];
      f32x4 b = *(const f32x4*)&Bsd[kk][tx * 4];
#pragma unroll
      for (int i = 0; i < 4; ++i)
#pragma unroll
        for (int j = 0; j < 4; ++j)
          acc[i][j] = fmaf(a[i], b[j], acc[i][j]);
    }
    __syncthreads();
  }

#pragma unroll
  for (int i = 0; i < 4; ++i){
    size_t m = m0 + ty * 4 + i;
#pragma unroll
    for (int j = 0; j < 4; ++j){
      int n = n0 + tx * 4 + j;
      size_t off = m * (size_t)N + n;
      float bv = (EPI != E_NONE) ? ldf(bias[n]) : 0.f;
      float vv = acc[i][j];
      if      (EPI == E_NONE)      ((u16*)C)[off] = f2bf(vv);
      else if (EPI == E_BIAS)      ((u16*)C)[off] = f2bf(vv + bv);
      else if (EPI == E_BIAS_GELU) ((u16*)C)[off] = f2bf(gelu_exact(vv + bv));
      else if (EPI == E_RES_F32)   accbuf[off] = vv + bv + ldf(res[off]);
      else if (EPI == E_ACC_F32)   accbuf[off] += vv + bv;
      else /* E_FINAL */           stf(&C[off], accbuf[off] + vv + bv);
    }
  }
}

extern "C" void kernel_launch(void* const* d_in, const int* in_sizes, int n_in,
                              void* d_out, int out_size, void* d_ws, size_t ws_size,
                              hipStream_t stream) {
  const u32* probe = (const u32*)d_in[1];   // norm1_scale (all ones)
  const int M = in_sizes[0] / DIM;          // 16384 tokens
  const int W11 = DIM * HID;                // 589824

  // bf16 views
  const u16 *x16 = (const u16*)d_in[0], *n1s16 = (const u16*)d_in[1], *n1b16 = (const u16*)d_in[2];
  const u16 *n2s16 = (const u16*)d_in[3], *n2b16 = (const u16*)d_in[4];
  const u16 *qw16 = (const u16*)d_in[5];
  const u16 *tw1_16 = (const u16*)d_in[6] + 4 * W11;
  const u16 *tb1_16 = (const u16*)d_in[7] + 4 * HID;
  const u16 *tw2_16 = (const u16*)d_in[8] + 4 * W11;
  const u16 *tb2_16 = (const u16*)d_in[9] + 4 * DIM;
  const u16 *ow16 = (const u16*)d_in[10], *ob16 = (const u16*)d_in[11];
  const u16 *cw1_16 = (const u16*)d_in[12], *cb1_16 = (const u16*)d_in[13];
  const u16 *cw2_16 = (const u16*)d_in[14], *cb2_16 = (const u16*)d_in[15];
  // f32 views
  const float *xf = (const float*)d_in[0], *n1sf = (const float*)d_in[1], *n1bf = (const float*)d_in[2];
  const float *n2sf = (const float*)d_in[3], *n2bf = (const float*)d_in[4];
  const float *qwf = (const float*)d_in[5];
  const float *tw1f = (const float*)d_in[6] + 4 * W11;
  const float *tb1f = (const float*)d_in[7] + 4 * HID;
  const float *tw2f = (const float*)d_in[8] + 4 * W11;
  const float *tb2f = (const float*)d_in[9] + 4 * DIM;
  const float *owf = (const float*)d_in[10], *obf = (const float*)d_in[11];
  const float *cw1f = (const float*)d_in[12], *cb1f = (const float*)d_in[13];
  const float *cw2f = (const float*)d_in[14], *cb2f = (const float*)d_in[15];
  const int *Tp = (const int*)d_in[16], *Hp = (const int*)d_in[17], *Wp = (const int*)d_in[18];

  // workspace: y(12.6MB) | h(50.3MB) | x2(25.2MB)  -> 88 MB
  char* ws = (char*)d_ws;
  u16*  y  = (u16*)(ws + 0);                  // M x 384 bf16 (y1, later y2)
  u16*  h  = (u16*)(ws + 12582912);           // M x 1536 bf16
  float* x2 = (float*)(ws + 62914560);        // M x 384 f32
  u16*  qb = (u16*)d_out;                     // q, then t1 (bf16 scratch in d_out)
  if (ws_size < 88080384u) return;

  dim3 g384(DIM/64, M/64), g1536(HID/64, M/64);

  // 1. y = LN1(x)
  ln_k<u16,u16><<<M/4,256,0,stream>>>(probe, 1, x16, n1s16, n1b16, y);
  ln_k<float,float><<<M/4,256,0,stream>>>(probe, 0, xf, n1sf, n1bf, y);
  // 2. q = y @ q_w      (bf16 into d_out)
  ngemm<u16,u16,E_NONE><<<g384,256,0,stream>>>(probe, 1, y, qw16, qb, nullptr, nullptr, nullptr, DIM, DIM);
  ngemm<float,u16,E_NONE><<<g384,256,0,stream>>>(probe, 0, y, qwf, qb, nullptr, nullptr, nullptr, DIM, DIM);
  // 3. RoPE(q) in place (mode-independent)
  rope_kernel<<<(M*192)/256,256,0,stream>>>(qb, Tp, Hp, Wp, M);
  // 4. h = gelu(q @ w1 + b1)
  ngemm<u16,u16,E_BIAS_GELU><<<g1536,256,0,stream>>>(probe, 1, qb, tw1_16, h, tb1_16, nullptr, nullptr, DIM, HID);
  ngemm<float,u16,E_BIAS_GELU><<<g1536,256,0,stream>>>(probe, 0, qb, tw1f, h, tb1f, nullptr, nullptr, DIM, HID);
  // 5. t1 = h @ w2 + b2   (bf16 into d_out, q dead)
  ngemm<u16,u16,E_BIAS><<<g384,256,0,stream>>>(probe, 1, h, tw2_16, qb, tb2_16, nullptr, nullptr, HID, DIM);
  ngemm<float,u16,E_BIAS><<<g384,256,0,stream>>>(probe, 0, h, tw2f, qb, tb2f, nullptr, nullptr, HID, DIM);
  // 6. x2 = x + t1 @ out_w + out_b   (f32)
  ngemm<u16,u16,E_RES_F32><<<g384,256,0,stream>>>(probe, 1, qb, ow16, (u16*)nullptr, ob16, x16, x2, DIM, DIM);
  ngemm<float,u16,E_RES_F32><<<g384,256,0,stream>>>(probe, 0, qb, owf, (u16*)nullptr, obf, xf, x2, DIM, DIM);
  // 7. y2 = LN2(x2)  (x2 is f32 in both modes; scale/bias are input dtype)
  ln_k<float,u16><<<M/4,256,0,stream>>>(probe, 1, x2, n2s16, n2b16, y);
  ln_k<float,float><<<M/4,256,0,stream>>>(probe, 0, x2, n2sf, n2bf, y);
  // 8. cms MLPs accumulate into x2; last emits output in I/O dtype
  for (int i = 0; i < 3; ++i){
    ngemm<u16,u16,E_BIAS_GELU><<<g1536,256,0,stream>>>(probe, 1, y, cw1_16 + i*W11, h, cb1_16 + i*HID, nullptr, nullptr, DIM, HID);
    ngemm<float,u16,E_BIAS_GELU><<<g1536,256,0,stream>>>(probe, 0, y, cw1f + i*W11, h, cb1f + i*HID, nullptr, nullptr, DIM, HID);
    if (i < 2){
      ngemm<u16,u16,E_ACC_F32><<<g384,256,0,stream>>>(probe, 1, h, cw2_16 + i*W11, (u16*)nullptr, cb2_16 + i*DIM, nullptr, x2, HID, DIM);
      ngemm<float,u16,E_ACC_F32><<<g384,256,0,stream>>>(probe, 0, h, cw2f + i*W11, (u16*)nullptr, cb2f + i*DIM, nullptr, x2, HID, DIM);
    } else {
      ngemm<u16,u16,E_FINAL><<<g384,256,0,stream>>>(probe, 1, h, cw2_16 + i*W11, (u16*)d_out, cb2_16 + i*DIM, nullptr, x2, HID, DIM);
      ngemm<float,float,E_FINAL><<<g384,256,0,stream>>>(probe, 0, h, cw2f + i*W11, (float*)d_out, cb2f + i*DIM, nullptr, x2, HID, DIM);
    }
  }
}

// Round 4
// 532.573 us; speedup vs baseline: 4.5029x; 4.5029x over previous
//
#include <hip/hip_runtime.h>
#include <math.h>

typedef unsigned short u16;
typedef unsigned int u32;
typedef __attribute__((ext_vector_type(8))) short short8;   // 8 bf16 (4 VGPRs)
typedef __attribute__((ext_vector_type(4))) float f32x4;

#define DIM 384
#define HID 1536

static __device__ __forceinline__ float bf2f(u32 b){ return __uint_as_float(b << 16); }
static __device__ __forceinline__ u16 f2bf(float f){
  u32 u = __float_as_uint(f);
  u32 r = (u + 0x7fffu + ((u >> 16) & 1u)) >> 16;
  return (u16)r;
}
static __device__ __forceinline__ float gelu_exact(float v){
  return 0.5f * v * (1.0f + erff(v * 0.70710678118654752f));
}

// ---------------- LayerNorm: f32 in, bf16 out ------------------------------
__global__ __launch_bounds__(256) void ln_kernel(const float* __restrict__ x,
    const float* __restrict__ sc, const float* __restrict__ bi, u16* __restrict__ y){
  int lane = threadIdx.x & 63;
  int row = blockIdx.x * 4 + (threadIdx.x >> 6);
  const float* xr = x + (size_t)row * DIM;
  float v[6];
  float s = 0.f, sq = 0.f;
#pragma unroll
  for (int i = 0; i < 6; ++i){
    float f = xr[lane + 64*i];
    v[i] = f; s += f; sq += f*f;
  }
#pragma unroll
  for (int o = 1; o < 64; o <<= 1){ s += __shfl_xor(s, o); sq += __shfl_xor(sq, o); }
  float mean = s * (1.0f/DIM);
  float var = sq * (1.0f/DIM) - mean*mean;
  float inv = rsqrtf(var + 1e-5f);
  u16* yr = y + (size_t)row * DIM;
#pragma unroll
  for (int i = 0; i < 6; ++i){
    int c = lane + 64*i;
    yr[c] = f2bf((v[i] - mean) * inv * sc[c] + bi[c]);
  }
}

// ---------------- 3D RoPE, in-place on q (bf16) ----------------------------
// per head (24 dims): [0,8)=t, [8,16)=h, [16,24)=w; pairs (2f,2f+1), f=0..3
__global__ __launch_bounds__(256) void rope_kernel(u16* __restrict__ q,
    const int* __restrict__ Tp, const int* __restrict__ Hp, const int* __restrict__ Wp,
    int Mtok){
  int idx = blockIdx.x * 256 + threadIdx.x;   // one thread per rotated pair
  int tok = idx / 192;                         // 192 pairs per token
  if (tok >= Mtok) return;
  int p = idx - tok * 192;
  int H = *Hp, W = *Wp, T = *Tp;
  int HW = H * W;
  int Ns = T * HW;
  int n = tok % Ns;
  int head = p / 12;
  int pp = p - head * 12;
  int s = pp >> 2, f = pp & 3;
  float pos;
  if (s == 0)      pos = (float)(n / HW);
  else if (s == 1) pos = (float)((n / W) % H);
  else             pos = (float)(n % W);
  const float LOG2_10000 = 13.28771237954945f;
  float inv = exp2f(-0.25f * (float)f * LOG2_10000);
  float ang = pos * inv;
  float sn = sinf(ang), cs = cosf(ang);
  size_t base = (size_t)tok * DIM + head * 24 + s * 8 + 2 * f;
  u32 u = *(u32*)(q + base);
  float x1 = bf2f(u & 0xffffu), x2 = bf2f(u >> 16);
  float y1 = x1 * cs - x2 * sn;
  float y2 = x1 * sn + x2 * cs;
  *(u32*)(q + base) = (u32)f2bf(y1) | ((u32)f2bf(y2) << 16);
}

// -------- weight transpose+convert: f32 in[R][C] -> bf16 out[C][R] ---------
template<int R, int C>
__global__ __launch_bounds__(256) void transpose_kernel(
    const float* __restrict__ s0, const float* __restrict__ s1,
    const float* __restrict__ s2, const float* __restrict__ s3,
    u16* __restrict__ d0, u16* __restrict__ d1, u16* __restrict__ d2, u16* __restrict__ d3){
  const float* src = (blockIdx.z == 0) ? s0 : (blockIdx.z == 1) ? s1 : (blockIdx.z == 2) ? s2 : s3;
  u16* dst         = (blockIdx.z == 0) ? d0 : (blockIdx.z == 1) ? d1 : (blockIdx.z == 2) ? d2 : d3;
  __shared__ u16 t[32][33];
  int tx = threadIdx.x & 31, ty = threadIdx.x >> 5;  // 32 x 8
  int r0 = blockIdx.y * 32, c0 = blockIdx.x * 32;
#pragma unroll
  for (int i = 0; i < 4; ++i)
    t[ty + 8*i][tx] = f2bf(src[(size_t)(r0 + ty + 8*i) * C + c0 + tx]);
  __syncthreads();
#pragma unroll
  for (int i = 0; i < 4; ++i)
    dst[(size_t)(c0 + ty + 8*i) * R + r0 + tx] = t[tx][ty + 8*i];
}

// ---------------- MFMA GEMM: C = A[M,K](bf16) @ Bt[N,K](bf16)^T ------------
// biases/res/accbuf are f32. Epilogue selects output form.
enum { E_NONE = 0, E_BIAS = 1, E_BIAS_GELU = 2, E_RES_F32 = 3, E_ACC_F32 = 4, E_FINAL = 5 };

template<int BM, int BN, int N, int K, int EPI>
__global__ __launch_bounds__(256) void gemm_kernel(
    const u16* __restrict__ A, const u16* __restrict__ Bt,
    void* __restrict__ Cv, const float* __restrict__ bias,
    const float* __restrict__ res, float* __restrict__ accbuf){
  constexpr int BK = 64;
  constexpr int MT = BM / 32, NT = BN / 32;   // 2x2 waves, each (BM/2)x(BN/2)
  __shared__ __align__(16) u16 As[BM * BK];
  __shared__ __align__(16) u16 Bs[BN * BK];
  const int tid = threadIdx.x;
  const int lane = tid & 63;
  const int wv = tid >> 6;
  const int wm = (wv >> 1) * (BM / 2);
  const int wn = (wv & 1) * (BN / 2);
  const int quad = lane >> 4;
  const int l16 = lane & 15;
  const size_t m0 = (size_t)blockIdx.x * BM;
  const int n0 = blockIdx.y * BN;

  f32x4 acc[MT][NT];
  const f32x4 zero = {0.f, 0.f, 0.f, 0.f};
#pragma unroll
  for (int mt = 0; mt < MT; ++mt)
#pragma unroll
    for (int nt = 0; nt < NT; ++nt) acc[mt][nt] = zero;

  constexpr int AIT = BM / 32;  // 16B-chunk iters to stage A (BM*BK/8 / 256)
  constexpr int BIT = BN / 32;

  for (int kt = 0; kt < K; kt += BK){
    short8 areg[AIT], breg[BIT];
#pragma unroll
    for (int i = 0; i < AIT; ++i){
      int ch = (i * 4 + wv) * 64 + lane;
      areg[i] = *(const short8*)(A + (m0 + (size_t)(ch >> 3)) * K + kt + (ch & 7) * 8);
    }
#pragma unroll
    for (int i = 0; i < BIT; ++i){
      int ch = (i * 4 + wv) * 64 + lane;
      breg[i] = *(const short8*)(Bt + (size_t)(n0 + (ch >> 3)) * K + kt + (ch & 7) * 8);
    }
    __syncthreads();   // previous iteration's fragment reads complete
#pragma unroll
    for (int i = 0; i < AIT; ++i){
      int ch = (i * 4 + wv) * 64 + lane;
      *(short8*)(As + ch * 8) = areg[i];
    }
#pragma unroll
    for (int i = 0; i < BIT; ++i){
      int ch = (i * 4 + wv) * 64 + lane;
      *(short8*)(Bs + ch * 8) = breg[i];
    }
    __syncthreads();
#pragma unroll
    for (int kk = 0; kk < 2; ++kk){
      short8 af[MT], bfr[NT];
#pragma unroll
      for (int mt = 0; mt < MT; ++mt)
        af[mt] = *(const short8*)(As + (wm + mt*16 + l16) * BK + kk*32 + quad*8);
#pragma unroll
      for (int nt = 0; nt < NT; ++nt)
        bfr[nt] = *(const short8*)(Bs + (wn + nt*16 + l16) * BK + kk*32 + quad*8);
#pragma unroll
      for (int mt = 0; mt < MT; ++mt)
#pragma unroll
        for (int nt = 0; nt < NT; ++nt)
          acc[mt][nt] = __builtin_amdgcn_mfma_f32_16x16x32_bf16(af[mt], bfr[nt], acc[mt][nt], 0, 0, 0);
    }
  }

  // epilogue: C/D mapping col = lane&15, row = quad*4 + reg  [m89-verified]
#pragma unroll
  for (int mt = 0; mt < MT; ++mt){
#pragma unroll
    for (int nt = 0; nt < NT; ++nt){
      int ncol = n0 + wn + nt*16 + l16;
      float bv = (EPI != E_NONE) ? bias[ncol] : 0.f;
      size_t mbase = m0 + wm + mt*16 + quad*4;
#pragma unroll
      for (int r = 0; r < 4; ++r){
        size_t off = (mbase + r) * N + ncol;
        float vv = acc[mt][nt][r];
        if      (EPI == E_NONE)      ((u16*)Cv)[off] = f2bf(vv);
        else if (EPI == E_BIAS)      ((u16*)Cv)[off] = f2bf(vv + bv);
        else if (EPI == E_BIAS_GELU) ((u16*)Cv)[off] = f2bf(gelu_exact(vv + bv));
        else if (EPI == E_RES_F32)   accbuf[off] = vv + bv + res[off];
        else if (EPI == E_ACC_F32)   accbuf[off] += vv + bv;
        else /* E_FINAL */           ((float*)Cv)[off] = accbuf[off] + vv + bv;
      }
    }
  }
}

extern "C" void kernel_launch(void* const* d_in, const int* in_sizes, int n_in,
                              void* d_out, int out_size, void* d_ws, size_t ws_size,
                              hipStream_t stream) {
  const int W11 = DIM * HID;   // 589824
  const float* x   = (const float*)d_in[0];
  const float* n1s = (const float*)d_in[1];
  const float* n1b = (const float*)d_in[2];
  const float* n2s = (const float*)d_in[3];
  const float* n2b = (const float*)d_in[4];
  const float* qw  = (const float*)d_in[5];
  const float* tw1 = (const float*)d_in[6] + 4 * W11;  // titan_w1[4]
  const float* tb1 = (const float*)d_in[7] + 4 * HID;  // titan_b1[4]
  const float* tw2 = (const float*)d_in[8] + 4 * W11;  // titan_w2[4]
  const float* tb2 = (const float*)d_in[9] + 4 * DIM;  // titan_b2[4]
  const float* ow  = (const float*)d_in[10];
  const float* ob  = (const float*)d_in[11];
  const float* cw1 = (const float*)d_in[12];
  const float* cb1 = (const float*)d_in[13];
  const float* cw2 = (const float*)d_in[14];
  const float* cb2 = (const float*)d_in[15];
  const int* Tp = (const int*)d_in[16];
  const int* Hp = (const int*)d_in[17];
  const int* Wp = (const int*)d_in[18];
  const int M = in_sizes[0] / DIM;   // 16384 tokens

  // workspace layout (bytes); round-1 evidence: ws_size >= 98107392
  char* ws = (char*)d_ws;
  u16*  y    = (u16*) (ws + 0);          // M x 384 bf16   (y1, later y2)
  u16*  h    = (u16*) (ws + 12582912);   // M x 1536 bf16
  float* x2  = (float*)(ws + 62914560);  // M x 384 f32    (residual spine)
  u16*  qwT  = (u16*) (ws + 88080384);   // 384 x 384
  u16*  owT  = (u16*) (ws + 88375296);   // 384 x 384
  u16*  w1T  = (u16*) (ws + 88670208);   // 1536 x 384
  u16*  w2T  = (u16*) (ws + 89849856);   // 384 x 1536
  u16*  cw1T = (u16*) (ws + 91029504);   // 3 x 1536 x 384
  u16*  cw2T = (u16*) (ws + 94568448);   // 3 x 384 x 1536
  u16*  qb   = (u16*)d_out;              // bf16 scratch: q, then t1 (overwritten by E_FINAL)
  if (ws_size < 98107392u) return;

  // 1. transpose+convert weights to bf16 [N][K]
  transpose_kernel<384,384><<<dim3(12,12,2),256,0,stream>>>(qw, ow, qw, qw, qwT, owT, qwT, qwT);
  transpose_kernel<384,1536><<<dim3(48,12,4),256,0,stream>>>(
      tw1, cw1, cw1 + W11, cw1 + 2*W11, w1T, cw1T, cw1T + W11, cw1T + 2*W11);
  transpose_kernel<1536,384><<<dim3(12,48,4),256,0,stream>>>(
      tw2, cw2, cw2 + W11, cw2 + 2*W11, w2T, cw2T, cw2T + W11, cw2T + 2*W11);

  // 2. y = LN1(x)
  ln_kernel<<<M/4,256,0,stream>>>(x, n1s, n1b, y);
  // 3. q = y @ q_w   (bf16, into d_out)
  gemm_kernel<64,128,384,384,E_NONE><<<dim3(M/64,3),256,0,stream>>>(y, qwT, qb, nullptr, nullptr, nullptr);
  // 4. RoPE(q) in-place
  rope_kernel<<<(M*192)/256,256,0,stream>>>(qb, Tp, Hp, Wp, M);
  // 5. h = gelu(q @ w1 + b1)
  gemm_kernel<128,128,1536,384,E_BIAS_GELU><<<dim3(M/128,12),256,0,stream>>>(qb, w1T, h, tb1, nullptr, nullptr);
  // 6. t1 = h @ w2 + b2   (bf16, into d_out)
  gemm_kernel<64,128,384,1536,E_BIAS><<<dim3(M/64,3),256,0,stream>>>(h, w2T, qb, tb2, nullptr, nullptr);
  // 7. x2 = x + t1 @ out_w + out_b   (f32)
  gemm_kernel<64,128,384,384,E_RES_F32><<<dim3(M/64,3),256,0,stream>>>(qb, owT, nullptr, ob, x, x2);
  // 8. y2 = LN2(x2)
  ln_kernel<<<M/4,256,0,stream>>>(x2, n2s, n2b, y);
  // 9. cms MLPs accumulate into x2; last emits f32 output
  for (int i = 0; i < 3; ++i){
    gemm_kernel<128,128,1536,384,E_BIAS_GELU><<<dim3(M/128,12),256,0,stream>>>(
        y, cw1T + i*W11, h, cb1 + i*HID, nullptr, nullptr);
    if (i < 2)
      gemm_kernel<64,128,384,1536,E_ACC_F32><<<dim3(M/64,3),256,0,stream>>>(
          h, cw2T + i*W11, nullptr, cb2 + i*DIM, nullptr, x2);
    else
      gemm_kernel<64,128,384,1536,E_FINAL><<<dim3(M/64,3),256,0,stream>>>(
          h, cw2T + i*W11, d_out, cb2 + i*DIM, nullptr, x2);
  }
}

// Round 5
// 498.308 us; speedup vs baseline: 4.8125x; 1.0688x over previous
//
#include <hip/hip_runtime.h>
#include <math.h>

typedef unsigned short u16;
typedef unsigned int u32;
typedef __attribute__((ext_vector_type(8))) short short8;   // 8 bf16 (4 VGPRs)
typedef __attribute__((ext_vector_type(4))) float f32x4;

#define DIM 384
#define HID 1536

static __device__ __forceinline__ float bf2f(u32 b){ return __uint_as_float(b << 16); }
static __device__ __forceinline__ u16 f2bf(float f){
  u32 u = __float_as_uint(f);
  u32 r = (u + 0x7fffu + ((u >> 16) & 1u)) >> 16;
  return (u16)r;
}
static __device__ __forceinline__ float gelu_exact(float v){
  return 0.5f * v * (1.0f + erff(v * 0.70710678118654752f));
}

// ---------------- LayerNorm: f32 in, bf16 out ------------------------------
__global__ __launch_bounds__(256) void ln_kernel(const float* __restrict__ x,
    const float* __restrict__ sc, const float* __restrict__ bi, u16* __restrict__ y){
  int lane = threadIdx.x & 63;
  int row = blockIdx.x * 4 + (threadIdx.x >> 6);
  const float* xr = x + (size_t)row * DIM;
  float v[6];
  float s = 0.f, sq = 0.f;
#pragma unroll
  for (int i = 0; i < 6; ++i){
    float f = xr[lane + 64*i];
    v[i] = f; s += f; sq += f*f;
  }
#pragma unroll
  for (int o = 1; o < 64; o <<= 1){ s += __shfl_xor(s, o); sq += __shfl_xor(sq, o); }
  float mean = s * (1.0f/DIM);
  float var = sq * (1.0f/DIM) - mean*mean;
  float inv = rsqrtf(var + 1e-5f);
  u16* yr = y + (size_t)row * DIM;
#pragma unroll
  for (int i = 0; i < 6; ++i){
    int c = lane + 64*i;
    yr[c] = f2bf((v[i] - mean) * inv * sc[c] + bi[c]);
  }
}

// ---------------- 3D RoPE, in-place on q (bf16) ----------------------------
__global__ __launch_bounds__(256) void rope_kernel(u16* __restrict__ q,
    const int* __restrict__ Tp, const int* __restrict__ Hp, const int* __restrict__ Wp,
    int Mtok){
  int idx = blockIdx.x * 256 + threadIdx.x;   // one thread per rotated pair
  int tok = idx / 192;                         // 192 pairs per token
  if (tok >= Mtok) return;
  int p = idx - tok * 192;
  int H = *Hp, W = *Wp, T = *Tp;
  int HW = H * W;
  int Ns = T * HW;
  int n = tok % Ns;
  int head = p / 12;
  int pp = p - head * 12;
  int s = pp >> 2, f = pp & 3;
  float pos;
  if (s == 0)      pos = (float)(n / HW);
  else if (s == 1) pos = (float)((n / W) % H);
  else             pos = (float)(n % W);
  const float LOG2_10000 = 13.28771237954945f;
  float inv = exp2f(-0.25f * (float)f * LOG2_10000);
  float ang = pos * inv;
  float sn = sinf(ang), cs = cosf(ang);
  size_t base = (size_t)tok * DIM + head * 24 + s * 8 + 2 * f;
  u32 u = *(u32*)(q + base);
  float x1 = bf2f(u & 0xffffu), x2 = bf2f(u >> 16);
  float y1 = x1 * cs - x2 * sn;
  float y2 = x1 * sn + x2 * cs;
  *(u32*)(q + base) = (u32)f2bf(y1) | ((u32)f2bf(y2) << 16);
}

// -------- weight transpose+convert: f32 in[R][C] -> bf16 out[C][R] ---------
template<int R, int C>
__global__ __launch_bounds__(256) void transpose_kernel(
    const float* __restrict__ s0, const float* __restrict__ s1,
    const float* __restrict__ s2, const float* __restrict__ s3,
    u16* __restrict__ d0, u16* __restrict__ d1, u16* __restrict__ d2, u16* __restrict__ d3){
  const float* src = (blockIdx.z == 0) ? s0 : (blockIdx.z == 1) ? s1 : (blockIdx.z == 2) ? s2 : s3;
  u16* dst         = (blockIdx.z == 0) ? d0 : (blockIdx.z == 1) ? d1 : (blockIdx.z == 2) ? d2 : d3;
  __shared__ u16 t[32][33];
  int tx = threadIdx.x & 31, ty = threadIdx.x >> 5;  // 32 x 8
  int r0 = blockIdx.y * 32, c0 = blockIdx.x * 32;
#pragma unroll
  for (int i = 0; i < 4; ++i)
    t[ty + 8*i][tx] = f2bf(src[(size_t)(r0 + ty + 8*i) * C + c0 + tx]);
  __syncthreads();
#pragma unroll
  for (int i = 0; i < 4; ++i)
    dst[(size_t)(c0 + ty + 8*i) * R + r0 + tx] = t[tx][ty + 8*i];
}

// ---------------- MFMA GEMM: C = A[M,K](bf16) @ Bt[N,K](bf16)^T ------------
// 128x128 tile, BK=64, LDS leading dim padded 64->72 u16 (kills the 16-way
// bank conflict: row stride 144B = 36 banks, rows shift 4 banks -> 2-way=free)
enum { E_NONE = 0, E_BIAS = 1, E_BIAS_GELU = 2, E_RES_F32 = 3, E_ACC_F32 = 4, E_FINAL = 5 };

template<int N, int K, int EPI>
__global__ __launch_bounds__(256) void gemm_kernel(
    const u16* __restrict__ A, const u16* __restrict__ Bt,
    void* __restrict__ Cv, const float* __restrict__ bias,
    const float* __restrict__ res, float* __restrict__ accbuf){
  constexpr int BM = 128, BN = 128, BK = 64;
  constexpr int BKP = 72;                     // padded leading dim (u16)
  constexpr int MT = 4, NT = 4;               // 2x2 waves, each 64x64
  __shared__ __align__(16) u16 As[BM * BKP];
  __shared__ __align__(16) u16 Bs[BN * BKP];
  const int tid = threadIdx.x;
  const int lane = tid & 63;
  const int wv = tid >> 6;
  const int wm = (wv >> 1) * 64;
  const int wn = (wv & 1) * 64;
  const int quad = lane >> 4;
  const int l16 = lane & 15;
  const size_t m0 = (size_t)blockIdx.x * BM;
  const int n0 = blockIdx.y * BN;

  f32x4 acc[MT][NT];
  const f32x4 zero = {0.f, 0.f, 0.f, 0.f};
#pragma unroll
  for (int mt = 0; mt < MT; ++mt)
#pragma unroll
    for (int nt = 0; nt < NT; ++nt) acc[mt][nt] = zero;

  for (int kt = 0; kt < K; kt += BK){
    short8 areg[4], breg[4];
#pragma unroll
    for (int i = 0; i < 4; ++i){
      int ch = (i * 4 + wv) * 64 + lane;     // chunk id: row=ch>>3, col8=ch&7
      areg[i] = *(const short8*)(A + (m0 + (size_t)(ch >> 3)) * K + kt + (ch & 7) * 8);
      breg[i] = *(const short8*)(Bt + (size_t)(n0 + (ch >> 3)) * K + kt + (ch & 7) * 8);
    }
    __syncthreads();   // previous iteration's fragment reads complete
#pragma unroll
    for (int i = 0; i < 4; ++i){
      int ch = (i * 4 + wv) * 64 + lane;
      *(short8*)(As + (ch >> 3) * BKP + (ch & 7) * 8) = areg[i];
      *(short8*)(Bs + (ch >> 3) * BKP + (ch & 7) * 8) = breg[i];
    }
    __syncthreads();
#pragma unroll
    for (int kk = 0; kk < 2; ++kk){
      short8 af[MT], bfr[NT];
#pragma unroll
      for (int mt = 0; mt < MT; ++mt)
        af[mt] = *(const short8*)(As + (wm + mt*16 + l16) * BKP + kk*32 + quad*8);
#pragma unroll
      for (int nt = 0; nt < NT; ++nt)
        bfr[nt] = *(const short8*)(Bs + (wn + nt*16 + l16) * BKP + kk*32 + quad*8);
#pragma unroll
      for (int mt = 0; mt < MT; ++mt)
#pragma unroll
        for (int nt = 0; nt < NT; ++nt)
          acc[mt][nt] = __builtin_amdgcn_mfma_f32_16x16x32_bf16(af[mt], bfr[nt], acc[mt][nt], 0, 0, 0);
    }
  }

  // epilogue: C/D mapping col = lane&15, row = quad*4 + reg  [m89-verified]
#pragma unroll
  for (int mt = 0; mt < MT; ++mt){
#pragma unroll
    for (int nt = 0; nt < NT; ++nt){
      int ncol = n0 + wn + nt*16 + l16;
      float bv = (EPI != E_NONE) ? bias[ncol] : 0.f;
      size_t mbase = m0 + wm + mt*16 + quad*4;
#pragma unroll
      for (int r = 0; r < 4; ++r){
        size_t off = (mbase + r) * N + ncol;
        float vv = acc[mt][nt][r];
        if      (EPI == E_NONE)      ((u16*)Cv)[off] = f2bf(vv);
        else if (EPI == E_BIAS)      ((u16*)Cv)[off] = f2bf(vv + bv);
        else if (EPI == E_BIAS_GELU) ((u16*)Cv)[off] = f2bf(gelu_exact(vv + bv));
        else if (EPI == E_RES_F32)   accbuf[off] = vv + bv + res[off];
        else if (EPI == E_ACC_F32)   accbuf[off] += vv + bv;
        else /* E_FINAL */           ((float*)Cv)[off] = accbuf[off] + vv + bv;
      }
    }
  }
}

extern "C" void kernel_launch(void* const* d_in, const int* in_sizes, int n_in,
                              void* d_out, int out_size, void* d_ws, size_t ws_size,
                              hipStream_t stream) {
  const int W11 = DIM * HID;   // 589824
  const float* x   = (const float*)d_in[0];
  const float* n1s = (const float*)d_in[1];
  const float* n1b = (const float*)d_in[2];
  const float* n2s = (const float*)d_in[3];
  const float* n2b = (const float*)d_in[4];
  const float* qw  = (const float*)d_in[5];
  const float* tw1 = (const float*)d_in[6] + 4 * W11;  // titan_w1[4]
  const float* tb1 = (const float*)d_in[7] + 4 * HID;  // titan_b1[4]
  const float* tw2 = (const float*)d_in[8] + 4 * W11;  // titan_w2[4]
  const float* tb2 = (const float*)d_in[9] + 4 * DIM;  // titan_b2[4]
  const float* ow  = (const float*)d_in[10];
  const float* ob  = (const float*)d_in[11];
  const float* cw1 = (const float*)d_in[12];
  const float* cb1 = (const float*)d_in[13];
  const float* cw2 = (const float*)d_in[14];
  const float* cb2 = (const float*)d_in[15];
  const int* Tp = (const int*)d_in[16];
  const int* Hp = (const int*)d_in[17];
  const int* Wp = (const int*)d_in[18];
  const int M = in_sizes[0] / DIM;   // 16384 tokens

  // workspace layout (bytes)
  char* ws = (char*)d_ws;
  u16*  y    = (u16*) (ws + 0);          // M x 384 bf16   (y1, later y2)
  u16*  h    = (u16*) (ws + 12582912);   // M x 1536 bf16
  float* x2  = (float*)(ws + 62914560);  // M x 384 f32    (residual spine)
  u16*  qwT  = (u16*) (ws + 88080384);   // 384 x 384
  u16*  owT  = (u16*) (ws + 88375296);   // 384 x 384
  u16*  w1T  = (u16*) (ws + 88670208);   // 1536 x 384
  u16*  w2T  = (u16*) (ws + 89849856);   // 384 x 1536
  u16*  cw1T = (u16*) (ws + 91029504);   // 3 x 1536 x 384
  u16*  cw2T = (u16*) (ws + 94568448);   // 3 x 384 x 1536
  u16*  qb   = (u16*)d_out;              // bf16 scratch: q, then t1 (overwritten by E_FINAL)
  if (ws_size < 98107392u) return;

  // 1. transpose+convert weights to bf16 [N][K]
  transpose_kernel<384,384><<<dim3(12,12,2),256,0,stream>>>(qw, ow, qw, qw, qwT, owT, qwT, qwT);
  transpose_kernel<384,1536><<<dim3(48,12,4),256,0,stream>>>(
      tw1, cw1, cw1 + W11, cw1 + 2*W11, w1T, cw1T, cw1T + W11, cw1T + 2*W11);
  transpose_kernel<1536,384><<<dim3(12,48,4),256,0,stream>>>(
      tw2, cw2, cw2 + W11, cw2 + 2*W11, w2T, cw2T, cw2T + W11, cw2T + 2*W11);

  // 2. y = LN1(x)
  ln_kernel<<<M/4,256,0,stream>>>(x, n1s, n1b, y);
  // 3. q = y @ q_w   (bf16, into d_out)
  gemm_kernel<384,384,E_NONE><<<dim3(M/128,3),256,0,stream>>>(y, qwT, qb, nullptr, nullptr, nullptr);
  // 4. RoPE(q) in-place
  rope_kernel<<<(M*192)/256,256,0,stream>>>(qb, Tp, Hp, Wp, M);
  // 5. h = gelu(q @ w1 + b1)
  gemm_kernel<1536,384,E_BIAS_GELU><<<dim3(M/128,12),256,0,stream>>>(qb, w1T, h, tb1, nullptr, nullptr);
  // 6. t1 = h @ w2 + b2   (bf16, into d_out)
  gemm_kernel<384,1536,E_BIAS><<<dim3(M/128,3),256,0,stream>>>(h, w2T, qb, tb2, nullptr, nullptr);
  // 7. x2 = x + t1 @ out_w + out_b   (f32)
  gemm_kernel<384,384,E_RES_F32><<<dim3(M/128,3),256,0,stream>>>(qb, owT, nullptr, ob, x, x2);
  // 8. y2 = LN2(x2)
  ln_kernel<<<M/4,256,0,stream>>>(x2, n2s, n2b, y);
  // 9. cms MLPs accumulate into x2; last emits f32 output
  for (int i = 0; i < 3; ++i){
    gemm_kernel<1536,384,E_BIAS_GELU><<<dim3(M/128,12),256,0,stream>>>(
        y, cw1T + i*W11, h, cb1 + i*HID, nullptr, nullptr);
    if (i < 2)
      gemm_kernel<384,1536,E_ACC_F32><<<dim3(M/128,3),256,0,stream>>>(
          h, cw2T + i*W11, nullptr, cb2 + i*DIM, nullptr, x2);
    else
      gemm_kernel<384,1536,E_FINAL><<<dim3(M/128,3),256,0,stream>>>(
          h, cw2T + i*W11, d_out, cb2 + i*DIM, nullptr, x2);
  }
}

// Round 6
// 493.079 us; speedup vs baseline: 4.8635x; 1.0106x over previous
//
#include <hip/hip_runtime.h>
#include <math.h>

typedef unsigned short u16;
typedef unsigned int u32;
typedef __attribute__((ext_vector_type(8))) short short8;   // 8 bf16 (4 VGPRs)
typedef __attribute__((ext_vector_type(4))) float f32x4;

#define DIM 384
#define HID 1536

static __device__ __forceinline__ float bf2f(u32 b){ return __uint_as_float(b << 16); }
static __device__ __forceinline__ u16 f2bf(float f){
  u32 u = __float_as_uint(f);
  u32 r = (u + 0x7fffu + ((u >> 16) & 1u)) >> 16;
  return (u16)r;
}
// tanh-form GELU as sigmoid: gelu(x) = x * sigmoid(1.5957691x + 0.0713548x^3)
// |err vs exact| < ~3e-4 abs; operating range |x|<~2 here -> ~1e-4.
static __device__ __forceinline__ float gelu_fast(float v){
  float u = v * fmaf(0.0713548162726f, v * v, 1.59576912161f);  // 2*0.79788456*(v+0.044715v^3)/v form
  float e = exp2f(-1.44269504089f * u);                          // e^{-u}
  return v * __builtin_amdgcn_rcpf(1.0f + e);
}
// async global->LDS, 16B/lane; LDS dest = wave-uniform base + lane*16
static __device__ __forceinline__ void gload_lds16(const u16* g, u16* l){
  __builtin_amdgcn_global_load_lds(
      (__attribute__((address_space(1))) void*)(void*)const_cast<u16*>(g),
      (__attribute__((address_space(3))) void*)(void*)l, 16, 0, 0);
}

// ---------------- LayerNorm: f32 in, bf16 out ------------------------------
__global__ __launch_bounds__(256) void ln_kernel(const float* __restrict__ x,
    const float* __restrict__ sc, const float* __restrict__ bi, u16* __restrict__ y){
  int lane = threadIdx.x & 63;
  int row = blockIdx.x * 4 + (threadIdx.x >> 6);
  const float* xr = x + (size_t)row * DIM;
  float v[6];
  float s = 0.f, sq = 0.f;
#pragma unroll
  for (int i = 0; i < 6; ++i){
    float f = xr[lane + 64*i];
    v[i] = f; s += f; sq += f*f;
  }
#pragma unroll
  for (int o = 1; o < 64; o <<= 1){ s += __shfl_xor(s, o); sq += __shfl_xor(sq, o); }
  float mean = s * (1.0f/DIM);
  float var = sq * (1.0f/DIM) - mean*mean;
  float inv = rsqrtf(var + 1e-5f);
  u16* yr = y + (size_t)row * DIM;
#pragma unroll
  for (int i = 0; i < 6; ++i){
    int c = lane + 64*i;
    yr[c] = f2bf((v[i] - mean) * inv * sc[c] + bi[c]);
  }
}

// ---------------- 3D RoPE, in-place on q (bf16) ----------------------------
__global__ __launch_bounds__(256) void rope_kernel(u16* __restrict__ q,
    const int* __restrict__ Tp, const int* __restrict__ Hp, const int* __restrict__ Wp,
    int Mtok){
  int idx = blockIdx.x * 256 + threadIdx.x;   // one thread per rotated pair
  int tok = idx / 192;                         // 192 pairs per token
  if (tok >= Mtok) return;
  int p = idx - tok * 192;
  int H = *Hp, W = *Wp, T = *Tp;
  int HW = H * W;
  int Ns = T * HW;
  int n = tok % Ns;
  int head = p / 12;
  int pp = p - head * 12;
  int s = pp >> 2, f = pp & 3;
  float pos;
  if (s == 0)      pos = (float)(n / HW);
  else if (s == 1) pos = (float)((n / W) % H);
  else             pos = (float)(n % W);
  const float LOG2_10000 = 13.28771237954945f;
  float inv = exp2f(-0.25f * (float)f * LOG2_10000);
  float ang = pos * inv;
  float sn = sinf(ang), cs = cosf(ang);
  size_t base = (size_t)tok * DIM + head * 24 + s * 8 + 2 * f;
  u32 u = *(u32*)(q + base);
  float x1 = bf2f(u & 0xffffu), x2 = bf2f(u >> 16);
  float y1 = x1 * cs - x2 * sn;
  float y2 = x1 * sn + x2 * cs;
  *(u32*)(q + base) = (u32)f2bf(y1) | ((u32)f2bf(y2) << 16);
}

// -------- weight transpose+convert: f32 in[R][C] -> bf16 out[C][R'] --------
// dst element (c, r) written at dst[c*dstStride + r]  (dstStride >= R)
template<int R, int C>
__global__ __launch_bounds__(256) void transpose_kernel(
    const float* __restrict__ s0, const float* __restrict__ s1,
    const float* __restrict__ s2, const float* __restrict__ s3,
    u16* __restrict__ d0, u16* __restrict__ d1, u16* __restrict__ d2, u16* __restrict__ d3,
    int dstStride){
  const float* src = (blockIdx.z == 0) ? s0 : (blockIdx.z == 1) ? s1 : (blockIdx.z == 2) ? s2 : s3;
  u16* dst         = (blockIdx.z == 0) ? d0 : (blockIdx.z == 1) ? d1 : (blockIdx.z == 2) ? d2 : d3;
  __shared__ u16 t[32][33];
  int tx = threadIdx.x & 31, ty = threadIdx.x >> 5;  // 32 x 8
  int r0 = blockIdx.y * 32, c0 = blockIdx.x * 32;
#pragma unroll
  for (int i = 0; i < 4; ++i)
    t[ty + 8*i][tx] = f2bf(src[(size_t)(r0 + ty + 8*i) * C + c0 + tx]);
  __syncthreads();
#pragma unroll
  for (int i = 0; i < 4; ++i)
    dst[(size_t)(c0 + ty + 8*i) * dstStride + r0 + tx] = t[tx][ty + 8*i];
}

// ---------------- sum 3 bias vectors of 384 --------------------------------
__global__ void bias3_kernel(const float* __restrict__ b, float* __restrict__ o){
  int n = threadIdx.x;
  o[n] = b[n] + b[384 + n] + b[768 + n];
}

// ---------------- MFMA GEMM: C = A[M,K](bf16) @ Bt[N,K](bf16)^T ------------
// m97-exact staging: global_load_lds width 16, unpadded [row][64] LDS,
// single buffer, 2 barriers per K-tile. BN=128 fixed; BM in {64,128}.
enum { E_NONE = 0, E_BIAS = 1, E_BIAS_GELU = 2, E_RES_F32 = 3, E_ACC_F32 = 4, E_FINAL = 5 };

template<int BM, int N, int K, int EPI>
__global__ __launch_bounds__(256) void gemm_kernel(
    const u16* __restrict__ A, const u16* __restrict__ Bt,
    void* __restrict__ Cv, const float* __restrict__ bias,
    const float* __restrict__ res, float* __restrict__ accbuf){
  constexpr int BN = 128, BK = 64;
  constexpr int MT = BM / 32, NT = 4;         // 2x2 waves, wave tile (BM/2)x64
  constexpr int AIT = BM / 32, BIT = 4;       // staging segs per wave
  __shared__ __align__(16) u16 As[BM * BK];
  __shared__ __align__(16) u16 Bs[BN * BK];
  const int tid = threadIdx.x;
  const int lane = tid & 63;
  const int wv = tid >> 6;
  const int wm = (wv >> 1) * (BM / 2);
  const int wn = (wv & 1) * 64;
  const int quad = lane >> 4;
  const int l16 = lane & 15;
  const size_t m0 = (size_t)blockIdx.x * BM;
  const int n0 = blockIdx.y * BN;

  f32x4 acc[MT][NT];
  const f32x4 zero = {0.f, 0.f, 0.f, 0.f};
#pragma unroll
  for (int mt = 0; mt < MT; ++mt)
#pragma unroll
    for (int nt = 0; nt < NT; ++nt) acc[mt][nt] = zero;

  for (int kt = 0; kt < K; kt += BK){
    // async stage: seg = 8 rows x 64 cols = 1024B; lane i -> base + i*16
#pragma unroll
    for (int i = 0; i < AIT; ++i){
      int seg = i * 4 + wv;
      int ch = seg * 64 + lane;
      gload_lds16(A + (m0 + (size_t)(ch >> 3)) * K + kt + (ch & 7) * 8, As + seg * 512);
    }
#pragma unroll
    for (int i = 0; i < BIT; ++i){
      int seg = i * 4 + wv;
      int ch = seg * 64 + lane;
      gload_lds16(Bt + (size_t)(n0 + (ch >> 3)) * K + kt + (ch & 7) * 8, Bs + seg * 512);
    }
    __syncthreads();   // drains vmcnt (loads landed) + lgkm
#pragma unroll
    for (int kk = 0; kk < 2; ++kk){
      short8 af[MT], bfr[NT];
#pragma unroll
      for (int mt = 0; mt < MT; ++mt)
        af[mt] = *(const short8*)(As + (wm + mt*16 + l16) * BK + kk*32 + quad*8);
#pragma unroll
      for (int nt = 0; nt < NT; ++nt)
        bfr[nt] = *(const short8*)(Bs + (wn + nt*16 + l16) * BK + kk*32 + quad*8);
#pragma unroll
      for (int mt = 0; mt < MT; ++mt)
#pragma unroll
        for (int nt = 0; nt < NT; ++nt)
          acc[mt][nt] = __builtin_amdgcn_mfma_f32_16x16x32_bf16(af[mt], bfr[nt], acc[mt][nt], 0, 0, 0);
    }
    __syncthreads();   // LDS safe to overwrite next iter
  }

  // epilogue: C/D mapping col = lane&15, row = quad*4 + reg  [m89-verified]
#pragma unroll
  for (int mt = 0; mt < MT; ++mt){
#pragma unroll
    for (int nt = 0; nt < NT; ++nt){
      int ncol = n0 + wn + nt*16 + l16;
      float bv = (EPI != E_NONE) ? bias[ncol] : 0.f;
      size_t mbase = m0 + wm + mt*16 + quad*4;
#pragma unroll
      for (int r = 0; r < 4; ++r){
        size_t off = (mbase + r) * N + ncol;
        float vv = acc[mt][nt][r];
        if      (EPI == E_NONE)      ((u16*)Cv)[off] = f2bf(vv);
        else if (EPI == E_BIAS)      ((u16*)Cv)[off] = f2bf(vv + bv);
        else if (EPI == E_BIAS_GELU) ((u16*)Cv)[off] = f2bf(gelu_fast(vv + bv));
        else if (EPI == E_RES_F32)   accbuf[off] = vv + bv + res[off];
        else if (EPI == E_ACC_F32)   accbuf[off] += vv + bv;
        else /* E_FINAL */           ((float*)Cv)[off] = accbuf[off] + vv + bv;
      }
    }
  }
}

extern "C" void kernel_launch(void* const* d_in, const int* in_sizes, int n_in,
                              void* d_out, int out_size, void* d_ws, size_t ws_size,
                              hipStream_t stream) {
  const int W11 = DIM * HID;   // 589824
  const float* x   = (const float*)d_in[0];
  const float* n1s = (const float*)d_in[1];
  const float* n1b = (const float*)d_in[2];
  const float* n2s = (const float*)d_in[3];
  const float* n2b = (const float*)d_in[4];
  const float* qw  = (const float*)d_in[5];
  const float* tw1 = (const float*)d_in[6] + 4 * W11;  // titan_w1[4]
  const float* tb1 = (const float*)d_in[7] + 4 * HID;  // titan_b1[4]
  const float* tw2 = (const float*)d_in[8] + 4 * W11;  // titan_w2[4]
  const float* tb2 = (const float*)d_in[9] + 4 * DIM;  // titan_b2[4]
  const float* ow  = (const float*)d_in[10];
  const float* ob  = (const float*)d_in[11];
  const float* cw1 = (const float*)d_in[12];
  const float* cb1 = (const float*)d_in[13];
  const float* cw2 = (const float*)d_in[14];
  const float* cb2 = (const float*)d_in[15];
  const int* Tp = (const int*)d_in[16];
  const int* Hp = (const int*)d_in[17];
  const int* Wp = (const int*)d_in[18];
  const int M = in_sizes[0] / DIM;   // 16384 tokens
  const bool fused = (ws_size >= 198772224u);   // fixed per problem -> graph-safe

  char* ws = (char*)d_ws;
  u16 *y, *h, *qwT, *owT, *w1T, *w2T, *cw1T, *cw2T;
  float *x2, *cb2s = nullptr;
  u16* qb = (u16*)d_out;   // bf16 scratch: q, then t1; overwritten by E_FINAL f32
  if (fused){
    y    = (u16*) (ws + 0);            // M x 384 bf16
    h    = (u16*) (ws + 12582912);     // M x 4608 bf16 (h_cat)
    x2   = (float*)(ws + 163577856);   // M x 384 f32
    qwT  = (u16*) (ws + 188743680);    // 384 x 384
    owT  = (u16*) (ws + 189038592);    // 384 x 384
    w1T  = (u16*) (ws + 189333504);    // 1536 x 384
    w2T  = (u16*) (ws + 190513152);    // 384 x 1536
    cw1T = (u16*) (ws + 191692800);    // 4608 x 384 (3 stacked, contiguous)
    cw2T = (u16*) (ws + 195231744);    // 384 x 4608 (K-stacked)
    cb2s = (float*)(ws + 198770688);   // 384 f32
  } else {
    if (ws_size < 98107392u) return;
    y    = (u16*) (ws + 0);
    h    = (u16*) (ws + 12582912);     // M x 1536 bf16
    x2   = (float*)(ws + 62914560);
    qwT  = (u16*) (ws + 88080384);
    owT  = (u16*) (ws + 88375296);
    w1T  = (u16*) (ws + 88670208);
    w2T  = (u16*) (ws + 89849856);
    cw1T = (u16*) (ws + 91029504);     // 3 x (1536 x 384)
    cw2T = (u16*) (ws + 94568448);     // 3 x (384 x 1536)
  }

  // 1. transpose+convert weights to bf16 [N][K]
  transpose_kernel<384,384><<<dim3(12,12,2),256,0,stream>>>(
      qw, ow, qw, qw, qwT, owT, qwT, qwT, 384);
  transpose_kernel<384,1536><<<dim3(48,12,4),256,0,stream>>>(
      tw1, cw1, cw1 + W11, cw1 + 2*W11, w1T, cw1T, cw1T + W11, cw1T + 2*W11, 384);
  if (fused){
    transpose_kernel<1536,384><<<dim3(12,48,1),256,0,stream>>>(
        tw2, tw2, tw2, tw2, w2T, w2T, w2T, w2T, 1536);
    transpose_kernel<1536,384><<<dim3(12,48,3),256,0,stream>>>(
        cw2, cw2 + W11, cw2 + 2*W11, cw2, cw2T, cw2T + 1536, cw2T + 3072, cw2T, 4608);
    bias3_kernel<<<1,384,0,stream>>>(cb2, cb2s);
  } else {
    transpose_kernel<1536,384><<<dim3(12,48,4),256,0,stream>>>(
        tw2, cw2, cw2 + W11, cw2 + 2*W11, w2T, cw2T, cw2T + W11, cw2T + 2*W11, 1536);
  }

  // 2. y = LN1(x)
  ln_kernel<<<M/4,256,0,stream>>>(x, n1s, n1b, y);
  // 3. q = y @ q_w   (bf16, into d_out)
  gemm_kernel<64,384,384,E_NONE><<<dim3(M/64,3),256,0,stream>>>(y, qwT, qb, nullptr, nullptr, nullptr);
  // 4. RoPE(q) in-place
  rope_kernel<<<(M*192)/256,256,0,stream>>>(qb, Tp, Hp, Wp, M);
  // 5. h = gelu(q @ w1 + b1)
  gemm_kernel<128,1536,384,E_BIAS_GELU><<<dim3(M/128,12),256,0,stream>>>(qb, w1T, h, tb1, nullptr, nullptr);
  // 6. t1 = h @ w2 + b2   (bf16, into d_out)
  gemm_kernel<64,384,1536,E_BIAS><<<dim3(M/64,3),256,0,stream>>>(h, w2T, qb, tb2, nullptr, nullptr);
  // 7. x2 = x + t1 @ out_w + out_b   (f32)
  gemm_kernel<64,384,384,E_RES_F32><<<dim3(M/64,3),256,0,stream>>>(qb, owT, nullptr, ob, x, x2);
  // 8. y2 = LN2(x2)
  ln_kernel<<<M/4,256,0,stream>>>(x2, n2s, n2b, y);
  // 9. cms MLPs
  if (fused){
    // h_cat = gelu(y @ [w1_0|w1_1|w1_2] + [b1]) : one N=4608 GEMM
    gemm_kernel<128,4608,384,E_BIAS_GELU><<<dim3(M/128,36),256,0,stream>>>(
        y, cw1T, h, cb1, nullptr, nullptr);
    // out = x2 + h_cat @ W2_stack + sum(b2): one K=4608 GEMM
    gemm_kernel<64,384,4608,E_FINAL><<<dim3(M/64,3),256,0,stream>>>(
        h, cw2T, d_out, cb2s, nullptr, x2);
  } else {
    for (int i = 0; i < 3; ++i){
      gemm_kernel<128,1536,384,E_BIAS_GELU><<<dim3(M/128,12),256,0,stream>>>(
          y, cw1T + i*W11, h, cb1 + i*HID, nullptr, nullptr);
      if (i < 2)
        gemm_kernel<64,384,1536,E_ACC_F32><<<dim3(M/64,3),256,0,stream>>>(
            h, cw2T + i*W11, nullptr, cb2 + i*DIM, nullptr, x2);
      else
        gemm_kernel<64,384,1536,E_FINAL><<<dim3(M/64,3),256,0,stream>>>(
            h, cw2T + i*W11, d_out, cb2 + i*DIM, nullptr, x2);
    }
  }
}

// Round 7
// 434.259 us; speedup vs baseline: 5.5223x; 1.1354x over previous
//
#include <hip/hip_runtime.h>
#include <math.h>

typedef unsigned short u16;
typedef unsigned int u32;
typedef __attribute__((ext_vector_type(8))) short short8;   // 8 bf16 (4 VGPRs)
typedef __attribute__((ext_vector_type(4))) float f32x4;

#define DIM 384
#define HID 1536

static __device__ __forceinline__ float bf2f(u32 b){ return __uint_as_float(b << 16); }
static __device__ __forceinline__ u16 f2bf(float f){
  u32 u = __float_as_uint(f);
  u32 r = (u + 0x7fffu + ((u >> 16) & 1u)) >> 16;
  return (u16)r;
}
// tanh-form GELU via sigmoid; |err| ~1e-4 in our operating range
static __device__ __forceinline__ float gelu_fast(float v){
  float u = v * fmaf(0.0713548162726f, v * v, 1.59576912161f);
  float e = exp2f(-1.44269504089f * u);
  return v * __builtin_amdgcn_rcpf(1.0f + e);
}
// async global->LDS, 16B/lane; LDS dest = wave-uniform base + lane*16
static __device__ __forceinline__ void gload_lds16(const u16* g, u16* l){
  __builtin_amdgcn_global_load_lds(
      (__attribute__((address_space(1))) void*)(void*)const_cast<u16*>(g),
      (__attribute__((address_space(3))) void*)(void*)l, 16, 0, 0);
}

// ---------------- LayerNorm: f32 in, bf16 out ------------------------------
__global__ __launch_bounds__(256) void ln_kernel(const float* __restrict__ x,
    const float* __restrict__ sc, const float* __restrict__ bi, u16* __restrict__ y){
  int lane = threadIdx.x & 63;
  int row = blockIdx.x * 4 + (threadIdx.x >> 6);
  const float* xr = x + (size_t)row * DIM;
  float v[6];
  float s = 0.f, sq = 0.f;
#pragma unroll
  for (int i = 0; i < 6; ++i){
    float f = xr[lane + 64*i];
    v[i] = f; s += f; sq += f*f;
  }
#pragma unroll
  for (int o = 1; o < 64; o <<= 1){ s += __shfl_xor(s, o); sq += __shfl_xor(sq, o); }
  float mean = s * (1.0f/DIM);
  float var = sq * (1.0f/DIM) - mean*mean;
  float inv = rsqrtf(var + 1e-5f);
  u16* yr = y + (size_t)row * DIM;
#pragma unroll
  for (int i = 0; i < 6; ++i){
    int c = lane + 64*i;
    yr[c] = f2bf((v[i] - mean) * inv * sc[c] + bi[c]);
  }
}

// ---------------- 3D RoPE, in-place on q (bf16) ----------------------------
__global__ __launch_bounds__(256) void rope_kernel(u16* __restrict__ q,
    const int* __restrict__ Tp, const int* __restrict__ Hp, const int* __restrict__ Wp,
    int Mtok){
  int idx = blockIdx.x * 256 + threadIdx.x;   // one thread per rotated pair
  int tok = idx / 192;                         // 192 pairs per token
  if (tok >= Mtok) return;
  int p = idx - tok * 192;
  int H = *Hp, W = *Wp, T = *Tp;
  int HW = H * W;
  int Ns = T * HW;
  int n = tok % Ns;
  int head = p / 12;
  int pp = p - head * 12;
  int s = pp >> 2, f = pp & 3;
  float pos;
  if (s == 0)      pos = (float)(n / HW);
  else if (s == 1) pos = (float)((n / W) % H);
  else             pos = (float)(n % W);
  const float LOG2_10000 = 13.28771237954945f;
  float inv = exp2f(-0.25f * (float)f * LOG2_10000);
  float ang = pos * inv;
  float sn = sinf(ang), cs = cosf(ang);
  size_t base = (size_t)tok * DIM + head * 24 + s * 8 + 2 * f;
  u32 u = *(u32*)(q + base);
  float x1 = bf2f(u & 0xffffu), x2 = bf2f(u >> 16);
  float y1 = x1 * cs - x2 * sn;
  float y2 = x1 * sn + x2 * cs;
  *(u32*)(q + base) = (u32)f2bf(y1) | ((u32)f2bf(y2) << 16);
}

// -------- weight transpose+convert: f32 in[R][C] -> bf16 out[C][R'] --------
template<int R, int C>
__global__ __launch_bounds__(256) void transpose_kernel(
    const float* __restrict__ s0, const float* __restrict__ s1,
    const float* __restrict__ s2, const float* __restrict__ s3,
    u16* __restrict__ d0, u16* __restrict__ d1, u16* __restrict__ d2, u16* __restrict__ d3,
    int dstStride){
  const float* src = (blockIdx.z == 0) ? s0 : (blockIdx.z == 1) ? s1 : (blockIdx.z == 2) ? s2 : s3;
  u16* dst         = (blockIdx.z == 0) ? d0 : (blockIdx.z == 1) ? d1 : (blockIdx.z == 2) ? d2 : d3;
  __shared__ u16 t[32][33];
  int tx = threadIdx.x & 31, ty = threadIdx.x >> 5;  // 32 x 8
  int r0 = blockIdx.y * 32, c0 = blockIdx.x * 32;
#pragma unroll
  for (int i = 0; i < 4; ++i)
    t[ty + 8*i][tx] = f2bf(src[(size_t)(r0 + ty + 8*i) * C + c0 + tx]);
  __syncthreads();
#pragma unroll
  for (int i = 0; i < 4; ++i)
    dst[(size_t)(c0 + ty + 8*i) * dstStride + r0 + tx] = t[tx][ty + 8*i];
}

// ---------------- sum 3 bias vectors of 384 --------------------------------
__global__ void bias3_kernel(const float* __restrict__ b, float* __restrict__ o){
  int n = threadIdx.x;
  o[n] = b[n] + b[384 + n] + b[768 + n];
}

// ---------------- MFMA GEMM: C = A[M,K](bf16) @ Bt[N,K](bf16)^T ------------
// m97 staging (global_load_lds w16) + XOR-swizzled LDS: chunk c of row r
// stored at physical chunk c^(r&7). Kills the 16-way fragment-read conflict
// at zero LDS-size cost (16 lanes -> 8 chunk positions x 2 = 2-way = free).
enum { E_NONE = 0, E_BIAS = 1, E_BIAS_GELU = 2, E_RES_F32 = 3, E_ACC_F32 = 4, E_FINAL = 5 };

template<int BM, int N, int K, int EPI>
__global__ __launch_bounds__(256) void gemm_kernel(
    const u16* __restrict__ A, const u16* __restrict__ Bt,
    void* __restrict__ Cv, const float* __restrict__ bias,
    const float* __restrict__ res, float* __restrict__ accbuf){
  constexpr int BN = 128, BK = 64;
  constexpr int MT = BM / 32, NT = 4;         // 2x2 waves, wave tile (BM/2)x64
  constexpr int AIT = BM / 32, BIT = 4;       // staging segs per wave
  __shared__ __align__(16) u16 As[BM * BK];
  __shared__ __align__(16) u16 Bs[BN * BK];
  const int tid = threadIdx.x;
  const int lane = tid & 63;
  const int wv = tid >> 6;
  const int wm = (wv >> 1) * (BM / 2);
  const int wn = (wv & 1) * 64;
  const int quad = lane >> 4;
  const int l16 = lane & 15;
  const int rsw = l16 & 7;                    // row&7 for fragment swizzle
  const size_t m0 = (size_t)blockIdx.x * BM;
  const int n0 = blockIdx.y * BN;
  // staging-side swizzle: lane l of a segment covers row seg*8+(l>>3);
  // it must fetch source chunk (l&7)^(l>>3) so that physical chunk
  // (l&7) == srcchunk ^ (row&7).
  const int srow = lane >> 3;                 // row within segment (0..7)
  const int scol = ((lane & 7) ^ srow) * 8;   // source k-offset (u16)

  f32x4 acc[MT][NT];
  const f32x4 zero = {0.f, 0.f, 0.f, 0.f};
#pragma unroll
  for (int mt = 0; mt < MT; ++mt)
#pragma unroll
    for (int nt = 0; nt < NT; ++nt) acc[mt][nt] = zero;

  for (int kt = 0; kt < K; kt += BK){
#pragma unroll
    for (int i = 0; i < AIT; ++i){
      int seg = i * 4 + wv;
      gload_lds16(A + (m0 + (size_t)(seg * 8 + srow)) * K + kt + scol, As + seg * 512);
    }
#pragma unroll
    for (int i = 0; i < BIT; ++i){
      int seg = i * 4 + wv;
      gload_lds16(Bt + (size_t)(n0 + seg * 8 + srow) * K + kt + scol, Bs + seg * 512);
    }
    __syncthreads();   // drains vmcnt (loads landed)
#pragma unroll
    for (int kk = 0; kk < 2; ++kk){
      short8 af[MT], bfr[NT];
#pragma unroll
      for (int mt = 0; mt < MT; ++mt)
        af[mt] = *(const short8*)(As + (wm + mt*16 + l16) * BK + (((kk*4 + quad) ^ rsw) << 3));
#pragma unroll
      for (int nt = 0; nt < NT; ++nt)
        bfr[nt] = *(const short8*)(Bs + (wn + nt*16 + l16) * BK + (((kk*4 + quad) ^ rsw) << 3));
#pragma unroll
      for (int mt = 0; mt < MT; ++mt)
#pragma unroll
        for (int nt = 0; nt < NT; ++nt)
          acc[mt][nt] = __builtin_amdgcn_mfma_f32_16x16x32_bf16(af[mt], bfr[nt], acc[mt][nt], 0, 0, 0);
    }
    __syncthreads();   // LDS safe to overwrite next iter
  }

  // epilogue: C/D mapping col = lane&15, row = quad*4 + reg  [m89-verified]
#pragma unroll
  for (int mt = 0; mt < MT; ++mt){
#pragma unroll
    for (int nt = 0; nt < NT; ++nt){
      int ncol = n0 + wn + nt*16 + l16;
      float bv = (EPI != E_NONE) ? bias[ncol] : 0.f;
      size_t mbase = m0 + wm + mt*16 + quad*4;
#pragma unroll
      for (int r = 0; r < 4; ++r){
        size_t off = (mbase + r) * N + ncol;
        float vv = acc[mt][nt][r];
        if      (EPI == E_NONE)      ((u16*)Cv)[off] = f2bf(vv);
        else if (EPI == E_BIAS)      ((u16*)Cv)[off] = f2bf(vv + bv);
        else if (EPI == E_BIAS_GELU) ((u16*)Cv)[off] = f2bf(gelu_fast(vv + bv));
        else if (EPI == E_RES_F32)   accbuf[off] = vv + bv + res[off];
        else if (EPI == E_ACC_F32)   accbuf[off] += vv + bv;
        else /* E_FINAL */           ((float*)Cv)[off] = accbuf[off] + vv + bv;
      }
    }
  }
}

extern "C" void kernel_launch(void* const* d_in, const int* in_sizes, int n_in,
                              void* d_out, int out_size, void* d_ws, size_t ws_size,
                              hipStream_t stream) {
  const int W11 = DIM * HID;   // 589824
  const float* x   = (const float*)d_in[0];
  const float* n1s = (const float*)d_in[1];
  const float* n1b = (const float*)d_in[2];
  const float* n2s = (const float*)d_in[3];
  const float* n2b = (const float*)d_in[4];
  const float* qw  = (const float*)d_in[5];
  const float* tw1 = (const float*)d_in[6] + 4 * W11;  // titan_w1[4]
  const float* tb1 = (const float*)d_in[7] + 4 * HID;  // titan_b1[4]
  const float* tw2 = (const float*)d_in[8] + 4 * W11;  // titan_w2[4]
  const float* tb2 = (const float*)d_in[9] + 4 * DIM;  // titan_b2[4]
  const float* ow  = (const float*)d_in[10];
  const float* ob  = (const float*)d_in[11];
  const float* cw1 = (const float*)d_in[12];
  const float* cb1 = (const float*)d_in[13];
  const float* cw2 = (const float*)d_in[14];
  const float* cb2 = (const float*)d_in[15];
  const int* Tp = (const int*)d_in[16];
  const int* Hp = (const int*)d_in[17];
  const int* Wp = (const int*)d_in[18];
  const int M = in_sizes[0] / DIM;   // 16384 tokens
  const bool fused = (ws_size >= 198772224u);   // fixed per problem -> graph-safe

  char* ws = (char*)d_ws;
  u16 *y, *h, *qwT, *owT, *w1T, *w2T, *cw1T, *cw2T;
  float *x2, *cb2s = nullptr;
  u16* qb = (u16*)d_out;   // bf16 scratch: q, then t1; overwritten by E_FINAL f32
  if (fused){
    y    = (u16*) (ws + 0);            // M x 384 bf16
    h    = (u16*) (ws + 12582912);     // M x 4608 bf16 (h_cat)
    x2   = (float*)(ws + 163577856);   // M x 384 f32
    qwT  = (u16*) (ws + 188743680);    // 384 x 384
    owT  = (u16*) (ws + 189038592);    // 384 x 384
    w1T  = (u16*) (ws + 189333504);    // 1536 x 384
    w2T  = (u16*) (ws + 190513152);    // 384 x 1536
    cw1T = (u16*) (ws + 191692800);    // 4608 x 384 (3 stacked, contiguous)
    cw2T = (u16*) (ws + 195231744);    // 384 x 4608 (K-stacked)
    cb2s = (float*)(ws + 198770688);   // 384 f32
  } else {
    if (ws_size < 98107392u) return;
    y    = (u16*) (ws + 0);
    h    = (u16*) (ws + 12582912);     // M x 1536 bf16
    x2   = (float*)(ws + 62914560);
    qwT  = (u16*) (ws + 88080384);
    owT  = (u16*) (ws + 88375296);
    w1T  = (u16*) (ws + 88670208);
    w2T  = (u16*) (ws + 89849856);
    cw1T = (u16*) (ws + 91029504);     // 3 x (1536 x 384)
    cw2T = (u16*) (ws + 94568448);     // 3 x (384 x 1536)
  }

  // 1. transpose+convert weights to bf16 [N][K]
  transpose_kernel<384,384><<<dim3(12,12,2),256,0,stream>>>(
      qw, ow, qw, qw, qwT, owT, qwT, qwT, 384);
  transpose_kernel<384,1536><<<dim3(48,12,4),256,0,stream>>>(
      tw1, cw1, cw1 + W11, cw1 + 2*W11, w1T, cw1T, cw1T + W11, cw1T + 2*W11, 384);
  if (fused){
    transpose_kernel<1536,384><<<dim3(12,48,1),256,0,stream>>>(
        tw2, tw2, tw2, tw2, w2T, w2T, w2T, w2T, 1536);
    transpose_kernel<1536,384><<<dim3(12,48,3),256,0,stream>>>(
        cw2, cw2 + W11, cw2 + 2*W11, cw2, cw2T, cw2T + 1536, cw2T + 3072, cw2T, 4608);
    bias3_kernel<<<1,384,0,stream>>>(cb2, cb2s);
  } else {
    transpose_kernel<1536,384><<<dim3(12,48,4),256,0,stream>>>(
        tw2, cw2, cw2 + W11, cw2 + 2*W11, w2T, cw2T, cw2T + W11, cw2T + 2*W11, 1536);
  }

  // 2. y = LN1(x)
  ln_kernel<<<M/4,256,0,stream>>>(x, n1s, n1b, y);
  // 3. q = y @ q_w   (bf16, into d_out)
  gemm_kernel<64,384,384,E_NONE><<<dim3(M/64,3),256,0,stream>>>(y, qwT, qb, nullptr, nullptr, nullptr);
  // 4. RoPE(q) in-place
  rope_kernel<<<(M*192)/256,256,0,stream>>>(qb, Tp, Hp, Wp, M);
  // 5. h = gelu(q @ w1 + b1)
  gemm_kernel<128,1536,384,E_BIAS_GELU><<<dim3(M/128,12),256,0,stream>>>(qb, w1T, h, tb1, nullptr, nullptr);
  // 6. t1 = h @ w2 + b2   (bf16, into d_out)
  gemm_kernel<64,384,1536,E_BIAS><<<dim3(M/64,3),256,0,stream>>>(h, w2T, qb, tb2, nullptr, nullptr);
  // 7. x2 = x + t1 @ out_w + out_b   (f32)
  gemm_kernel<64,384,384,E_RES_F32><<<dim3(M/64,3),256,0,stream>>>(qb, owT, nullptr, ob, x, x2);
  // 8. y2 = LN2(x2)
  ln_kernel<<<M/4,256,0,stream>>>(x2, n2s, n2b, y);
  // 9. cms MLPs
  if (fused){
    gemm_kernel<128,4608,384,E_BIAS_GELU><<<dim3(M/128,36),256,0,stream>>>(
        y, cw1T, h, cb1, nullptr, nullptr);
    gemm_kernel<64,384,4608,E_FINAL><<<dim3(M/64,3),256,0,stream>>>(
        h, cw2T, d_out, cb2s, nullptr, x2);
  } else {
    for (int i = 0; i < 3; ++i){
      gemm_kernel<128,1536,384,E_BIAS_GELU><<<dim3(M/128,12),256,0,stream>>>(
          y, cw1T + i*W11, h, cb1 + i*HID, nullptr, nullptr);
      if (i < 2)
        gemm_kernel<64,384,1536,E_ACC_F32><<<dim3(M/64,3),256,0,stream>>>(
            h, cw2T + i*W11, nullptr, cb2 + i*DIM, nullptr, x2);
      else
        gemm_kernel<64,384,1536,E_FINAL><<<dim3(M/64,3),256,0,stream>>>(
            h, cw2T + i*W11, d_out, cb2 + i*DIM, nullptr, x2);
    }
  }
}